// Round 9
// baseline (275.398 us; speedup 1.0000x reference)
//
#include <hip/hip_runtime.h>
#include <stdint.h>

#define SEQ   512
#define NB    1024
#define NIN   64
#define NH    16
#define NCLS  6
#define GSTRIDE 20   // floats per gate row in LDS (16 data + 4 pad)
#define GBLK  32     // timesteps per group
#define NGRP  (SEQ / GBLK)

#define GBUF   (128 * GSTRIDE)        // floats per G buffer (one group, 128 rows)
#define GELEM  (2 * GBUF + 8)         // per-element G stride (+8: de-alias elements)
#define HTELEM (2 * GBLK * NH + 8)    // per-element HT stride (+8 pad)

typedef __attribute__((ext_vector_type(8))) short short8;
typedef __attribute__((ext_vector_type(4))) float f32x4;

// constants: gate pre-acts are pre-scaled so exp2 consumes them directly.
// i,f,o: z' = -log2e * z      -> sigma(z)  = rcp(1+exp2(z'))
// g:     z' = -2*log2e * z    -> sigma(2z) = rcp(1+exp2(z')); tanh(z)=2r-1
// c kept pre-scaled by K = -2*log2e (so exp2(C) = e^{-2c}).
#define LOG2E   1.4426950408889634f
#define NK_IFO  (-1.4426950408889634f)
#define NK_G    (-2.8853900817779268f)
#define KC      (-2.8853900817779268f)

// G chunk swizzle v2: physical chunk = logical chunk ^ GKEY2(row).
// ((row>>3)&3) spreads the 8-row bank-base period (as before); the ^(row>>5)
// term de-aliases row pairs (r, r+64-rows... i.e. units u, u+8) which share
// both bank base and old key under the packed-consumer read pattern.
// Invariant: GKEY2(row+64) == GKEY2(row) (64>>3 = 8 = 0 mod 4; 64>>5 = 2 = 0 mod 2),
// so one gidx serves both 16-step subtiles.
#define GKEY2(row) ((((row) >> 3) & 3) ^ (((row) >> 5) & 1))

// Split fp32 -> bf16 hi + bf16 lo (truncation split; residual ~2^-16 relative).
// NOTE (R5): inline-asm cvt_pk version regressed 82->103 us (asm perturbs
// hipcc scheduling). Keep the plain bit-twiddle form.
__device__ __forceinline__ void split8(float4 u0, float4 u1, short8& hi, short8& lo) {
    float f[8] = {u0.x, u0.y, u0.z, u0.w, u1.x, u1.y, u1.z, u1.w};
    #pragma unroll
    for (int j = 0; j < 8; ++j) {
        uint32_t b = __float_as_uint(f[j]);
        uint16_t hb = (uint16_t)(b >> 16);
        hi[j] = (short)hb;
        float hf = __uint_as_float(((uint32_t)hb) << 16);
        lo[j] = (short)(uint16_t)(__float_as_uint(f[j] - hf) >> 16);
    }
}

// producer helpers: load one 16-step x tile, compute one 16-step gate tile
#define LOAD_TILE(P0, P1, P2, P3, T) do {                       \
    const float* xp_ = xbase + (size_t)(T) * 16 * NIN;          \
    P0 = *(const float4*)(xp_ + 0);                             \
    P1 = *(const float4*)(xp_ + 4);                             \
    P2 = *(const float4*)(xp_ + 32);                            \
    P3 = *(const float4*)(xp_ + 36);                            \
} while (0)

#define COMPUTE_TILE(P0, P1, P2, P3, GB, ROWOFF) do {                          \
    short8 a0h_, a0l_, a1h_, a1l_;                                             \
    split8(P0, P1, a0h_, a0l_);                                                \
    split8(P2, P3, a1h_, a1l_);                                                \
    _Pragma("unroll")                                                          \
    for (int tau = 0; tau < 4; ++tau) {                                        \
        f32x4 c_ = {0.f, 0.f, 0.f, 0.f};                                       \
        c_ = __builtin_amdgcn_mfma_f32_16x16x32_bf16(a0h_, Bh[tau][0], c_, 0, 0, 0); \
        c_ = __builtin_amdgcn_mfma_f32_16x16x32_bf16(a1h_, Bh[tau][1], c_, 0, 0, 0); \
        c_ = __builtin_amdgcn_mfma_f32_16x16x32_bf16(a0l_, Bh[tau][0], c_, 0, 0, 0); \
        c_ = __builtin_amdgcn_mfma_f32_16x16x32_bf16(a0h_, Bl[tau][0], c_, 0, 0, 0); \
        c_ = __builtin_amdgcn_mfma_f32_16x16x32_bf16(a1l_, Bh[tau][1], c_, 0, 0, 0); \
        c_ = __builtin_amdgcn_mfma_f32_16x16x32_bf16(a1h_, Bl[tau][1], c_, 0, 0, 0); \
        f32x4 s_;                                                              \
        s_[0] = fmaf(c_[0], nkt[tau], bwk[tau]);                               \
        s_[1] = fmaf(c_[1], nkt[tau], bwk[tau]);                               \
        s_[2] = fmaf(c_[2], nkt[tau], bwk[tau]);                               \
        s_[3] = fmaf(c_[3], nkt[tau], bwk[tau]);                               \
        *(f32x4*)&(GB)[(ROWOFF) + gidx[tau]] = s_;                             \
    }                                                                          \
} while (0)

// packed-consumer h broadcast: src lane (within 32-lane half) = (lane&0x10)|J
// -> every lane of element eq receives unit J's h of its OWN element.
// One instruction serves all 4 packed elements (ds_swizzle is per-32-lane).
#define HSWZ(J) hs[J] = __int_as_float(__builtin_amdgcn_ds_swizzle(hni, (((J) << 5) | 0x10)))

// 16-term matvec for gate T, depth-5 (8 pairs + 3-level tree)
#define MATVEC(T, DST) do {                                                    \
    float q0 = fmaf(hs[0],  whh[T][0],  gvv[T][r8]);                           \
    q0       = fmaf(hs[1],  whh[T][1],  q0);                                   \
    float q1 = hs[2]  * whh[T][2];   q1 = fmaf(hs[3],  whh[T][3],  q1);        \
    float q2 = hs[4]  * whh[T][4];   q2 = fmaf(hs[5],  whh[T][5],  q2);        \
    float q3 = hs[6]  * whh[T][6];   q3 = fmaf(hs[7],  whh[T][7],  q3);        \
    float q4 = hs[8]  * whh[T][8];   q4 = fmaf(hs[9],  whh[T][9],  q4);        \
    float q5 = hs[10] * whh[T][10];  q5 = fmaf(hs[11], whh[T][11], q5);        \
    float q6 = hs[12] * whh[T][12];  q6 = fmaf(hs[13], whh[T][13], q6);        \
    float q7 = hs[14] * whh[T][14];  q7 = fmaf(hs[15], whh[T][15], q7);        \
    DST = ((q0 + q1) + (q2 + q3)) + ((q4 + q5) + (q6 + q7));                   \
} while (0)

__global__ __launch_bounds__(320, 2)
void lstm_ws_kernel(const float* __restrict__ x,
                    const float* __restrict__ w_ih,
                    const float* __restrict__ w_hh,
                    const float* __restrict__ b_ih,
                    const float* __restrict__ b_hh,
                    const float* __restrict__ w_fc,
                    const float* __restrict__ b_fc,
                    float* __restrict__ out)
{
    // flat, per-element-padded LDS (GELEM/HTELEM odd-ish strides de-alias
    // the 4 elements' bank bases for the packed consumer's reads/writes)
    __shared__ float Gf [4 * GELEM];    // ~80.2 KB, pre-scaled gates
    __shared__ float HTf[4 * HTELEM];   // ~16.1 KB, h history (per-step writes)

    const int tid  = threadIdx.x;
    const int wid  = tid >> 6;       // 0..4 (320 threads = 5 waves)
    const int lane = tid & 63;
    // waves 0-3: producers (one element each, SIMD 0-3).
    // wave 4: single packed consumer (4 chains lanewise), lands on SIMD0.
    // R4 taught: chains in separate waves interleave at 1.5x issue-share each;
    // chains packed lanewise share the SAME instructions -> latency paid once.
    const bool producer = (wid < 4);

    if (producer) {
        // ================= PRODUCER: x-GEMM + staging + FC =================
        const int e    = wid;
        const int b    = blockIdx.x * 4 + e;
        float* Ge  = &Gf [e * GELEM];
        float* HTe = &HTf[e * HTELEM];

        const int ml   = lane & 15;      // MFMA B col = unit
        const int half = lane >> 4;      // 0..3
        const int kk   = half * 8;

        short8 Bh[4][2], Bl[4][2];
        #pragma unroll
        for (int tau = 0; tau < 4; ++tau) {
            #pragma unroll
            for (int ch = 0; ch < 2; ++ch) {
                const float* wr = w_ih + (tau * 16 + ml) * NIN + ch * 32 + kk;
                float4 u0 = *(const float4*)wr;
                float4 u1 = *(const float4*)(wr + 4);
                split8(u0, u1, Bh[tau][ch], Bl[tau][ch]);
            }
        }
        float nkt[4], bwk[4];
        int   gidx[4];
        #pragma unroll
        for (int tau = 0; tau < 4; ++tau) {
            nkt[tau] = (tau == 2) ? NK_G : NK_IFO;
            bwk[tau] = (b_ih[tau * 16 + ml] + b_hh[tau * 16 + ml]) * nkt[tau];
            const int row = ml * 4 + tau;          // G row = unit*4 + gate
            gidx[tau] = row * GSTRIDE + (half ^ GKEY2(row)) * 4;
        }

        const float* xbase = x + ((size_t)b * SEQ + ml) * NIN + kk;

        float4 a0, a1, a2, a3;   // tile buffer A
        float4 b0, b1, b2, b3;   // tile buffer B

        // prologue: group 0 = tiles 0,1 -> buf0; prefetch tile 2
        LOAD_TILE(a0, a1, a2, a3, 0);
        LOAD_TILE(b0, b1, b2, b3, 1);
        COMPUTE_TILE(a0, a1, a2, a3, Ge, 0);
        LOAD_TILE(a0, a1, a2, a3, 2);
        COMPUTE_TILE(b0, b1, b2, b3, Ge, 64 * GSTRIDE);
        __syncthreads();   // barrier 0: G[0] ready

        float accfc[NCLS];
        #pragma unroll
        for (int cls = 0; cls < NCLS; ++cls) accfc[cls] = 0.f;

        for (int g = 0; g < NGRP; ++g) {
            if (g < NGRP - 1) {
                float* Gb = Ge + ((g + 1) & 1) * GBUF;
                LOAD_TILE(b0, b1, b2, b3, 2 * g + 3);
                COMPUTE_TILE(a0, a1, a2, a3, Gb, 0);
                if (g < NGRP - 2)
                    LOAD_TILE(a0, a1, a2, a3, 2 * g + 4);
                COMPUTE_TILE(b0, b1, b2, b3, Gb, 64 * GSTRIDE);
            }
            if (g > 0) {
                const int gp = g - 1;
                const float* ht = &HTe[(gp & 1) * (GBLK * NH)];
                float4 h4a = *(const float4*)&ht[lane * 4];
                float4 h4b = *(const float4*)&ht[256 + lane * 4];
                #pragma unroll
                for (int cls = 0; cls < NCLS; ++cls) {
                    const float* wf = w_fc + cls * (SEQ * NH) + gp * (GBLK * NH);
                    float4 wfa = *(const float4*)(wf + lane * 4);
                    float4 wfb = *(const float4*)(wf + 256 + lane * 4);
                    accfc[cls] = fmaf(h4a.x, wfa.x, accfc[cls]);
                    accfc[cls] = fmaf(h4a.y, wfa.y, accfc[cls]);
                    accfc[cls] = fmaf(h4a.z, wfa.z, accfc[cls]);
                    accfc[cls] = fmaf(h4a.w, wfa.w, accfc[cls]);
                    accfc[cls] = fmaf(h4b.x, wfb.x, accfc[cls]);
                    accfc[cls] = fmaf(h4b.y, wfb.y, accfc[cls]);
                    accfc[cls] = fmaf(h4b.z, wfb.z, accfc[cls]);
                    accfc[cls] = fmaf(h4b.w, wfb.w, accfc[cls]);
                }
            }
            __syncthreads();   // barrier g+1
        }
        {
            const int gp = NGRP - 1;
            const float* ht = &HTe[(gp & 1) * (GBLK * NH)];
            float4 h4a = *(const float4*)&ht[lane * 4];
            float4 h4b = *(const float4*)&ht[256 + lane * 4];
            #pragma unroll
            for (int cls = 0; cls < NCLS; ++cls) {
                const float* wf = w_fc + cls * (SEQ * NH) + gp * (GBLK * NH);
                float4 wfa = *(const float4*)(wf + lane * 4);
                float4 wfb = *(const float4*)(wf + 256 + lane * 4);
                accfc[cls] = fmaf(h4a.x, wfa.x, accfc[cls]);
                accfc[cls] = fmaf(h4a.y, wfa.y, accfc[cls]);
                accfc[cls] = fmaf(h4a.z, wfa.z, accfc[cls]);
                accfc[cls] = fmaf(h4a.w, wfa.w, accfc[cls]);
                accfc[cls] = fmaf(h4b.x, wfb.x, accfc[cls]);
                accfc[cls] = fmaf(h4b.y, wfb.y, accfc[cls]);
                accfc[cls] = fmaf(h4b.z, wfb.z, accfc[cls]);
                accfc[cls] = fmaf(h4b.w, wfb.w, accfc[cls]);
            }
        }
        #pragma unroll
        for (int cls = 0; cls < NCLS; ++cls) {
            float v = accfc[cls];
            v += __shfl_xor(v, 1);
            v += __shfl_xor(v, 2);
            v += __shfl_xor(v, 4);
            v += __shfl_xor(v, 8);
            v += __shfl_xor(v, 16);
            v += __shfl_xor(v, 32);
            accfc[cls] = v;
        }
        if (lane == 0) {
            #pragma unroll
            for (int cls = 0; cls < NCLS; ++cls)
                out[b * NCLS + cls] = accfc[cls] + b_fc[cls];
        }
    } else {
        // ====== CONSUMER: 4 recurrence chains packed lanewise in 1 wave ======
        // lane = 16*eq + u: element eq (0..3), hidden unit u (0..15).
        // Each lane computes ALL 4 gates of its unit: no DPP gate-gather,
        // latency paid once for 4 elements.
        const int eq = lane >> 4;
        const int u  = lane & 15;

        float whh[4][NH];
        int   rowoff[4], key[4];
        #pragma unroll
        for (int t = 0; t < 4; ++t) {
            const float nk = (t == 2) ? NK_G : NK_IFO;
            #pragma unroll
            for (int j = 0; j < NH; j += 4) {
                float4 w4 = *(const float4*)(w_hh + (t * 16 + u) * NH + j);
                whh[t][j]   = w4.x * nk;
                whh[t][j+1] = w4.y * nk;
                whh[t][j+2] = w4.z * nk;
                whh[t][j+3] = w4.w * nk;
            }
            const int row = u * 4 + t;
            rowoff[t] = row * GSTRIDE;
            key[t]    = GKEY2(row);
        }

        const float* Geq = &Gf [eq * GELEM];
        float*       HTq = &HTf[eq * HTELEM];

        float C = 0.f;
        float hs[NH];
        #pragma unroll
        for (int j = 0; j < NH; ++j) hs[j] = 0.f;

        // critical-path wave: priority over the SIMD-mate producer [T5]
        __builtin_amdgcn_s_setprio(1);

        __syncthreads();   // barrier 0: G[0] ready

        for (int g = 0; g < NGRP; ++g) {
            const float* Gb  = Geq + (g & 1) * GBUF;
            float*       HTw = HTq + (g & 1) * (GBLK * NH);

            #pragma unroll
            for (int k = 0; k < 4; ++k) {           // 8-step subchunks
                const int toff = (k >> 1) * (64 * GSTRIDE);   // 16-step subtile
                const int c0 = (2 * k) & 3, c1 = (2 * k + 1) & 3;
                float gvv[4][8];
                #pragma unroll
                for (int t = 0; t < 4; ++t) {
                    const float* rp = Gb + toff + rowoff[t];
                    f32x4 ga = *(const f32x4*)&rp[(c0 ^ key[t]) * 4];
                    f32x4 gb = *(const f32x4*)&rp[(c1 ^ key[t]) * 4];
                    gvv[t][0]=ga[0]; gvv[t][1]=ga[1]; gvv[t][2]=ga[2]; gvv[t][3]=ga[3];
                    gvv[t][4]=gb[0]; gvv[t][5]=gb[1]; gvv[t][6]=gb[2]; gvv[t][7]=gb[3];
                }

                #pragma unroll
                for (int r8 = 0; r8 < 8; ++r8) {
                    const int r = k * 8 + r8;
                    float z0, z1, z2, z3;
                    MATVEC(0, z0);
                    MATVEC(1, z1);
                    MATVEC(2, z2);
                    MATVEC(3, z3);

                    const float ei = __builtin_amdgcn_exp2f(z0);
                    const float ef = __builtin_amdgcn_exp2f(z1);
                    const float eg = __builtin_amdgcn_exp2f(z2);
                    const float eo = __builtin_amdgcn_exp2f(z3);
                    const float ai = __builtin_amdgcn_rcpf(1.f + ei);
                    const float af = __builtin_amdgcn_rcpf(1.f + ef);
                    const float rg = __builtin_amdgcn_rcpf(1.f + eg);
                    const float ao = __builtin_amdgcn_rcpf(1.f + eo);

                    const float ag  = fmaf(2.f * KC, rg, -KC);   // K*tanh(g)
                    const float igg = ai * ag;
                    C = fmaf(af, C, igg);                        // C = K*c

                    const float e2 = __builtin_amdgcn_exp2f(C);  // e^{-2c}
                    const float r2 = __builtin_amdgcn_rcpf(1.f + e2);
                    const float hn = fmaf(ao + ao, r2, -ao);     // o*tanh(c)

                    HTw[r * NH + u] = hn;   // off-chain publish for FC

                    const int hni = __float_as_int(hn);
                    HSWZ(0);  HSWZ(1);  HSWZ(2);  HSWZ(3);
                    HSWZ(4);  HSWZ(5);  HSWZ(6);  HSWZ(7);
                    HSWZ(8);  HSWZ(9);  HSWZ(10); HSWZ(11);
                    HSWZ(12); HSWZ(13); HSWZ(14); HSWZ(15);
                }
            }

            __syncthreads();   // barrier g+1 (HT[g&1] complete for FC)
        }
    }
}

extern "C" void kernel_launch(void* const* d_in, const int* in_sizes, int n_in,
                              void* d_out, int out_size, void* d_ws, size_t ws_size,
                              hipStream_t stream) {
    const float* x    = (const float*)d_in[0];
    const float* w_ih = (const float*)d_in[1];
    const float* w_hh = (const float*)d_in[2];
    const float* b_ih = (const float*)d_in[3];
    const float* b_hh = (const float*)d_in[4];
    const float* w_fc = (const float*)d_in[5];
    const float* b_fc = (const float*)d_in[6];
    float* out = (float*)d_out;

    hipLaunchKernelGGL(lstm_ws_kernel, dim3(NB / 4), dim3(320), 0, stream,
                       x, w_ih, w_hh, b_ih, b_hh, w_fc, b_fc, out);
}

// Round 10
// 220.894 us; speedup vs baseline: 1.2467x; 1.2467x over previous
//
#include <hip/hip_runtime.h>
#include <stdint.h>

#define SEQ   512
#define NB    1024
#define NIN   64
#define NH    16
#define NCLS  6
#define GSTRIDE 20   // floats per gate row in LDS (16 data + 4 pad)
#define GBLK  32     // timesteps per group
#define NGRP  (SEQ / GBLK)

typedef __attribute__((ext_vector_type(8))) short short8;
typedef __attribute__((ext_vector_type(4))) float f32x4;

// constants: gate pre-acts are pre-scaled so exp2 consumes them directly.
// i,f,o: z' = -log2e * z      -> sigma(z)  = rcp(1+exp2(z'))
// g:     z' = -2*log2e * z    -> sigma(2z) = rcp(1+exp2(z')); tanh(z)=2r-1
// c kept pre-scaled by K = -2*log2e (so exp2(C) = e^{-2c}); g-lane output
// constants fold K: act_g = K*tanh(g) = 2K*r - K.
#define LOG2E   1.4426950408889634f
#define NK_IFO  (-1.4426950408889634f)
#define NK_G    (-2.8853900817779268f)
#define KC      (-2.8853900817779268f)

// G chunk swizzle: physical chunk = logical chunk ^ ((row>>3)&3).
// Bank base (20*row mod 32) repeats with period 8; XOR-rotating the chunk
// spreads the 8 aliasing lanes across all 4 chunks -> 2-way max (free).
// Invariant: GKEY(row+64) == GKEY(row), so 128-row buffers need no change.
#define GKEY(row) (((row) >> 3) & 3)

// Split fp32 -> bf16 hi + bf16 lo (truncation split; residual ~2^-16 relative).
// NOTE (R5): an inline-asm v_cvt_pk_bf16_f32 version regressed 82->103 us —
// asm blocks perturb hipcc's scheduling/regalloc. Keep plain bit-twiddle.
__device__ __forceinline__ void split8(float4 u0, float4 u1, short8& hi, short8& lo) {
    float f[8] = {u0.x, u0.y, u0.z, u0.w, u1.x, u1.y, u1.z, u1.w};
    #pragma unroll
    for (int j = 0; j < 8; ++j) {
        uint32_t b = __float_as_uint(f[j]);
        uint16_t hb = (uint16_t)(b >> 16);
        hi[j] = (short)hb;
        float hf = __uint_as_float(((uint32_t)hb) << 16);
        lo[j] = (short)(uint16_t)(__float_as_uint(f[j] - hf) >> 16);
    }
}

__device__ __forceinline__ float readlane_f(float v, int l) {
    return __int_as_float(__builtin_amdgcn_readlane(__float_as_int(v), l));
}

// quad_perm broadcast via update_dpp (R4/R5-verified on gfx950)
__device__ __forceinline__ float quad_bcast0(float v) {
    return __int_as_float(__builtin_amdgcn_update_dpp(0, __float_as_int(v), 0x00, 0xF, 0xF, true));
}
__device__ __forceinline__ float quad_bcast1(float v) {
    return __int_as_float(__builtin_amdgcn_update_dpp(0, __float_as_int(v), 0x55, 0xF, 0xF, true));
}
__device__ __forceinline__ float quad_bcast2(float v) {
    return __int_as_float(__builtin_amdgcn_update_dpp(0, __float_as_int(v), 0xAA, 0xF, 0xF, true));
}
__device__ __forceinline__ float quad_bcast3(float v) {
    return __int_as_float(__builtin_amdgcn_update_dpp(0, __float_as_int(v), 0xFF, 0xF, 0xF, true));
}

// producer helpers: load one 16-step x tile, compute one 16-step gate tile
#define LOAD_TILE(P0, P1, P2, P3, T) do {                       \
    const float* xp_ = xbase + (size_t)(T) * 16 * NIN;          \
    P0 = *(const float4*)(xp_ + 0);                             \
    P1 = *(const float4*)(xp_ + 4);                             \
    P2 = *(const float4*)(xp_ + 32);                            \
    P3 = *(const float4*)(xp_ + 36);                            \
} while (0)

#define COMPUTE_TILE(P0, P1, P2, P3, GB, ROWOFF) do {                          \
    short8 a0h_, a0l_, a1h_, a1l_;                                             \
    split8(P0, P1, a0h_, a0l_);                                                \
    split8(P2, P3, a1h_, a1l_);                                                \
    _Pragma("unroll")                                                          \
    for (int tau = 0; tau < 4; ++tau) {                                        \
        f32x4 c_ = {0.f, 0.f, 0.f, 0.f};                                       \
        c_ = __builtin_amdgcn_mfma_f32_16x16x32_bf16(a0h_, Bh[tau][0], c_, 0, 0, 0); \
        c_ = __builtin_amdgcn_mfma_f32_16x16x32_bf16(a1h_, Bh[tau][1], c_, 0, 0, 0); \
        c_ = __builtin_amdgcn_mfma_f32_16x16x32_bf16(a0l_, Bh[tau][0], c_, 0, 0, 0); \
        c_ = __builtin_amdgcn_mfma_f32_16x16x32_bf16(a0h_, Bl[tau][0], c_, 0, 0, 0); \
        c_ = __builtin_amdgcn_mfma_f32_16x16x32_bf16(a1l_, Bh[tau][1], c_, 0, 0, 0); \
        c_ = __builtin_amdgcn_mfma_f32_16x16x32_bf16(a1h_, Bl[tau][1], c_, 0, 0, 0); \
        f32x4 s_;                                                              \
        s_[0] = fmaf(c_[0], nkt[tau], bwk[tau]);                               \
        s_[1] = fmaf(c_[1], nkt[tau], bwk[tau]);                               \
        s_[2] = fmaf(c_[2], nkt[tau], bwk[tau]);                               \
        s_[3] = fmaf(c_[3], nkt[tau], bwk[tau]);                               \
        *(f32x4*)&(GB)[(ROWOFF) + gidx[tau]] = s_;                             \
    }                                                                          \
} while (0)

__global__ __launch_bounds__(512, 2)
void lstm_ws_kernel(const float* __restrict__ x,
                    const float* __restrict__ w_ih,
                    const float* __restrict__ w_hh,
                    const float* __restrict__ b_ih,
                    const float* __restrict__ b_hh,
                    const float* __restrict__ w_fc,
                    const float* __restrict__ b_fc,
                    float* __restrict__ out)
{
    __shared__ float G [4][2][128 * GSTRIDE];   // 80 KB, pre-scaled gates (chunk-swizzled)
    __shared__ float HT[4][2][GBLK * NH];       // 16 KB, h history

    const int tid  = threadIdx.x;
    const int wid  = tid >> 6;       // 0..7
    const int lane = tid & 63;
    // R3 mapping (verified best): producer wid 0-3 pairs with consumer wid 4-7
    // on the same SIMD (wid%4). Alternatives all regressed: 2-consumers/SIMD
    // (R4, +50%), lanewise 4-chain packing (R9, +67%). Do not revisit.
    const int e    = wid & 3;        // batch element within block
    const int b    = blockIdx.x * 4 + e;
    const bool producer = (wid < 4);

    if (producer) {
        // ================= PRODUCER: x-GEMM + staging + FC =================
        const int ml   = lane & 15;      // MFMA A row (timestep) / B col
        const int half = lane >> 4;      // 0..3
        const int kk   = half * 8;

        short8 Bh[4][2], Bl[4][2];
        #pragma unroll
        for (int tau = 0; tau < 4; ++tau) {
            #pragma unroll
            for (int ch = 0; ch < 2; ++ch) {
                const float* wr = w_ih + (tau * 16 + ml) * NIN + ch * 32 + kk;
                float4 u0 = *(const float4*)wr;
                float4 u1 = *(const float4*)(wr + 4);
                split8(u0, u1, Bh[tau][ch], Bl[tau][ch]);
            }
        }
        // per-tile exp2 prescale + prescaled bias (gate row = tau*16 + ml; tau==2 is g)
        float nkt[4], bwk[4];
        int   gidx[4];   // swizzled slot for this lane's 4 G rows (subtile 0)
        #pragma unroll
        for (int tau = 0; tau < 4; ++tau) {
            nkt[tau] = (tau == 2) ? NK_G : NK_IFO;
            bwk[tau] = (b_ih[tau * 16 + ml] + b_hh[tau * 16 + ml]) * nkt[tau];
            const int row = ml * 4 + tau;
            gidx[tau] = row * GSTRIDE + (half ^ GKEY(row)) * 4;
        }

        const float* xbase = x + ((size_t)b * SEQ + ml) * NIN + kk;

        float4 a0, a1, a2, a3;   // tile buffer A
        float4 b0, b1, b2, b3;   // tile buffer B

        // prologue: group 0 = tiles 0,1 -> G[e][0]; prefetch tile 2
        LOAD_TILE(a0, a1, a2, a3, 0);
        LOAD_TILE(b0, b1, b2, b3, 1);
        COMPUTE_TILE(a0, a1, a2, a3, G[e][0], 0);
        LOAD_TILE(a0, a1, a2, a3, 2);
        COMPUTE_TILE(b0, b1, b2, b3, G[e][0], 64 * GSTRIDE);
        __syncthreads();   // barrier 0: G[0] ready

        float accfc[NCLS];
        #pragma unroll
        for (int cls = 0; cls < NCLS; ++cls) accfc[cls] = 0.f;

        for (int g = 0; g < NGRP; ++g) {
            if (g < NGRP - 1) {
                // group g+1 = tiles 2g+2 (in A regs), 2g+3
                LOAD_TILE(b0, b1, b2, b3, 2 * g + 3);
                COMPUTE_TILE(a0, a1, a2, a3, G[e][(g + 1) & 1], 0);
                if (g < NGRP - 2)
                    LOAD_TILE(a0, a1, a2, a3, 2 * g + 4);
                COMPUTE_TILE(b0, b1, b2, b3, G[e][(g + 1) & 1], 64 * GSTRIDE);
            }
            if (g > 0) {
                const int gp = g - 1;
                float4 h4a = *(float4*)&HT[e][gp & 1][lane * 4];
                float4 h4b = *(float4*)&HT[e][gp & 1][256 + lane * 4];
                #pragma unroll
                for (int cls = 0; cls < NCLS; ++cls) {
                    const float* wf = w_fc + cls * (SEQ * NH) + gp * (GBLK * NH);
                    float4 wfa = *(const float4*)(wf + lane * 4);
                    float4 wfb = *(const float4*)(wf + 256 + lane * 4);
                    accfc[cls] = fmaf(h4a.x, wfa.x, accfc[cls]);
                    accfc[cls] = fmaf(h4a.y, wfa.y, accfc[cls]);
                    accfc[cls] = fmaf(h4a.z, wfa.z, accfc[cls]);
                    accfc[cls] = fmaf(h4a.w, wfa.w, accfc[cls]);
                    accfc[cls] = fmaf(h4b.x, wfb.x, accfc[cls]);
                    accfc[cls] = fmaf(h4b.y, wfb.y, accfc[cls]);
                    accfc[cls] = fmaf(h4b.z, wfb.z, accfc[cls]);
                    accfc[cls] = fmaf(h4b.w, wfb.w, accfc[cls]);
                }
            }
            __syncthreads();   // barrier g+1
        }
        {
            const int gp = NGRP - 1;
            float4 h4a = *(float4*)&HT[e][gp & 1][lane * 4];
            float4 h4b = *(float4*)&HT[e][gp & 1][256 + lane * 4];
            #pragma unroll
            for (int cls = 0; cls < NCLS; ++cls) {
                const float* wf = w_fc + cls * (SEQ * NH) + gp * (GBLK * NH);
                float4 wfa = *(const float4*)(wf + lane * 4);
                float4 wfb = *(const float4*)(wf + 256 + lane * 4);
                accfc[cls] = fmaf(h4a.x, wfa.x, accfc[cls]);
                accfc[cls] = fmaf(h4a.y, wfa.y, accfc[cls]);
                accfc[cls] = fmaf(h4a.z, wfa.z, accfc[cls]);
                accfc[cls] = fmaf(h4a.w, wfa.w, accfc[cls]);
                accfc[cls] = fmaf(h4b.x, wfb.x, accfc[cls]);
                accfc[cls] = fmaf(h4b.y, wfb.y, accfc[cls]);
                accfc[cls] = fmaf(h4b.z, wfb.z, accfc[cls]);
                accfc[cls] = fmaf(h4b.w, wfb.w, accfc[cls]);
            }
        }
        #pragma unroll
        for (int cls = 0; cls < NCLS; ++cls) {
            float v = accfc[cls];
            v += __shfl_xor(v, 1);
            v += __shfl_xor(v, 2);
            v += __shfl_xor(v, 4);
            v += __shfl_xor(v, 8);
            v += __shfl_xor(v, 16);
            v += __shfl_xor(v, 32);
            accfc[cls] = v;
        }
        if (lane == 0) {
            #pragma unroll
            for (int cls = 0; cls < NCLS; ++cls)
                out[b * NCLS + cls] = accfc[cls] + b_fc[cls];
        }
    } else {
        // ================= CONSUMER: pure recurrence chain =================
        // lane = u*4 + gate  (gate: 0=i,1=f,2=g,3=o)
        const int gate_t = lane & 3;
        const int u      = lane >> 2;
        const int grow   = gate_t * 16 + u;
        const float nkl  = (gate_t == 2) ? NK_G : NK_IFO;    // matches producer prescale
        float whh[NH];
        #pragma unroll
        for (int j = 0; j < NH; j += 4) {
            float4 w4 = *(const float4*)(w_hh + grow * NH + j);
            whh[j]   = w4.x * nkl;
            whh[j+1] = w4.y * nkl;
            whh[j+2] = w4.z * nkl;
            whh[j+3] = w4.w * nkl;
        }
        // output constants: i,f,o -> sigma; g -> K*tanh  (K folded so C is pre-scaled)
        const bool  isg = (gate_t == 2);
        const float sO  = isg ? (2.f * KC) : 1.f;
        const float sB  = isg ? (-KC)      : 0.f;

        // swizzled chunk key for this lane's G rows
        const int gkey = GKEY(lane);

        // h broadcast: 16x v_readlane. A/B/C-tested vs ds_bpermute (R7, +3%)
        // and LDS roundtrip (R8, +9%) — readlane is the fastest variant.
        float C = 0.f;                 // pre-scaled cell state: C = K * c
        float hs[NH];
        #pragma unroll
        for (int j = 0; j < NH; ++j) hs[j] = 0.f;

        // Consumer wave is the critical path 100% of the time. [T5, +4% R3]
        __builtin_amdgcn_s_setprio(1);

        __syncthreads();   // barrier 0: G[0] ready

        for (int g = 0; g < NGRP; ++g) {
            float gvv[GBLK];
            #pragma unroll
            for (int q = 0; q < 8; ++q) {
                f32x4 g4 = *(f32x4*)&G[e][g & 1][(q >> 2) * 64 * GSTRIDE +
                                                 lane * GSTRIDE + (((q & 3) ^ gkey) * 4)];
                gvv[q*4+0] = g4[0]; gvv[q*4+1] = g4[1]; gvv[q*4+2] = g4[2]; gvv[q*4+3] = g4[3];
            }

            float hstore[GBLK];

            #pragma unroll
            for (int r = 0; r < GBLK; ++r) {
                // matvec: z' = gvv' + (whh*nk)·h, depth-5 (8 pairs + 3-level tree)
                float p0 = fmaf(hs[0],  whh[0],  gvv[r]);
                p0       = fmaf(hs[1],  whh[1],  p0);
                float p1 = hs[2]  * whh[2];   p1 = fmaf(hs[3],  whh[3],  p1);
                float p2 = hs[4]  * whh[4];   p2 = fmaf(hs[5],  whh[5],  p2);
                float p3 = hs[6]  * whh[6];   p3 = fmaf(hs[7],  whh[7],  p3);
                float p4 = hs[8]  * whh[8];   p4 = fmaf(hs[9],  whh[9],  p4);
                float p5 = hs[10] * whh[10];  p5 = fmaf(hs[11], whh[11], p5);
                float p6 = hs[12] * whh[12];  p6 = fmaf(hs[13], whh[13], p6);
                float p7 = hs[14] * whh[14];  p7 = fmaf(hs[15], whh[15], p7);
                const float s01 = p0 + p1, s23 = p2 + p3, s45 = p4 + p5, s67 = p6 + p7;
                const float zp  = (s01 + s23) + (s45 + s67);

                // act: i,f,o -> sigma(z); g -> K*tanh(z)   (exp2 arg pre-scaled)
                const float ex  = __builtin_amdgcn_exp2f(zp);
                const float act = fmaf(sO, __builtin_amdgcn_rcpf(1.f + ex), sB);

                // gather within 4-lane cluster (VALU DPP)
                const float ig = quad_bcast0(act);
                const float fg = quad_bcast1(act);
                const float gg = quad_bcast2(act);   // = K*tanh(g)
                const float og = quad_bcast3(act);

                // off-chain helpers during the exp2 latency
                const float igg = ig * gg;           // K * i * tanh(g)
                const float t2o = og + og;
                const float nog = -og;

                // pre-scaled cell update: C = f*C + K*i*tanh(g)  (C = K*c)
                C = fmaf(fg, C, igg);
                // h = o * tanh(c) = 2*o*rcp(1+e^{-2c}) - o ; exp2(C) = e^{-2c}
                const float e2 = __builtin_amdgcn_exp2f(C);
                const float r2 = __builtin_amdgcn_rcpf(1.f + e2);
                const float hn = fmaf(t2o, r2, nog);

                hstore[r] = hn;

                #pragma unroll
                for (int j = 0; j < NH; ++j) hs[j] = readlane_f(hn, 4 * j);
            }

            // batch h history to LDS. hn identical across the 4-lane cluster
            // -> only gate_t==0 lanes store.
            if (gate_t == 0) {
                #pragma unroll
                for (int r = 0; r < GBLK; ++r)
                    HT[e][g & 1][r * NH + u] = hstore[r];
            }

            __syncthreads();   // barrier g+1
        }
    }
}

extern "C" void kernel_launch(void* const* d_in, const int* in_sizes, int n_in,
                              void* d_out, int out_size, void* d_ws, size_t ws_size,
                              hipStream_t stream) {
    const float* x    = (const float*)d_in[0];
    const float* w_ih = (const float*)d_in[1];
    const float* w_hh = (const float*)d_in[2];
    const float* b_ih = (const float*)d_in[3];
    const float* b_hh = (const float*)d_in[4];
    const float* w_fc = (const float*)d_in[5];
    const float* b_fc = (const float*)d_in[6];
    float* out = (float*)d_out;

    hipLaunchKernelGGL(lstm_ws_kernel, dim3(NB / 4), dim3(512), 0, stream,
                       x, w_ih, w_hh, b_ih, b_hh, w_fc, b_fc, out);
}